// Round 2
// 643.133 us; speedup vs baseline: 1.0610x; 1.0610x over previous
//
#include <hip/hip_runtime.h>

// ---------------------------------------------------------------------------
// VQ-VAE forward — split-fp16 MFMA everywhere.
// x = h + l*2^-11 (l prescaled by 2^11), w likewise; acc1 = h*wh,
// acc2 = h*wl + l*wh; result = acc1 + acc2/2048.  (fp32-accurate)
// Verified MFMA mapping: A[m=lane&15][k=quad*8+j] (8 consecutive k),
// B rows [n][kk] (8 consecutive kk at col n=lane&15), D col=lane&15,
// row=quad*4+reg.  kk = ci*4 + tap, tap padded to 4 with zero weights.
// R3 lesson: NEVER index register arrays with runtime values (BH[d] spilled
// to scratch -> 766 MB of HBM writes). All buffer indices now compile-time.
// R4 change: conv1 rewritten BARRIER-FREE + LDS-FREE. Old version was
// latency-bound (MfmaUtil 3.4%, HBM 11%, 2 barriers x 24 chunks, 52KB LDS
// -> 3 blocks/CU). Each lane now loads its A-fragment window
// x[ci][2m-1..2m+2] directly from global (scalar + aligned float2 + scalar;
// 2m-1 odd => 2m is 8B-aligned), splits in registers, feeds MFMA. Window
// overlap = 2x L1 traffic, HBM still 1x. M-tile 64, each wave does both
// 16-col tiles (NTW=2) so A loads amortize over 2x MFMA.
// R5: resubmit of R4 unchanged — R4 bench was an infra failure (container
// acquire failed twice), no kernel signal. OOB/layout re-audited: clean.
// ---------------------------------------------------------------------------

typedef _Float16 half8 __attribute__((ext_vector_type(8)));
typedef float f32x4 __attribute__((ext_vector_type(4)));
union H8u { half8 h; int4 i; };
union P4u { _Float16 e[4]; int2 u; };

__device__ __forceinline__ void splitf(float v, _Float16& h, _Float16& l) {
  h = (_Float16)v; l = (_Float16)((v - (float)h) * 2048.0f);
}
#define INV2048 (1.0f / 2048.0f)

// ---- prepped-weight layout offsets (f16 elements) ----
#define OFF_C1   0        // conv1  [32][3072]
#define OFF_C2   98304    // conv2  [64][128]
#define OFF_C3   106496   // conv3  [64][256]
#define OFF_ER0A 122880   // enc r0 conv3 [32][256]
#define OFF_ER0B 131072   // enc r0 1x1   [64][32]
#define OFF_ER1A 133120
#define OFF_ER1B 141312
#define OFF_PQ   143360   // prevq [64][64]
#define OFF_DW1  147456   // dec conv1 [64][256]
#define OFF_DR0A 163840
#define OFF_DR0B 172032
#define OFF_DR1A 174080
#define OFF_DR1B 182272
#define OFF_T1   184320   // convT1 [64=par*32+co][256]
#define OFF_T2   200704   // convT2 [128=par*64+co][128]
#define WTOT     217088

struct WPtrs {
  const float *c1, *c2, *c3, *er0a, *er0b, *er1a, *er1b, *pq,
              *dw1, *dr0a, *dr0b, *dr1a, *dr1b, *t1, *t2;
};

__device__ __forceinline__ int tpose_kt(int par, int tap) {
  if (par == 0) { if (tap == 0) return 3; if (tap == 1) return 1; }
  else          { if (tap == 1) return 2; if (tap == 2) return 0; }
  return -1;
}

__global__ __launch_bounds__(256) void prep_k(WPtrs P, _Float16* __restrict__ WH,
                                              _Float16* __restrict__ WL) {
  int s = blockIdx.x * 256 + threadIdx.x;
  if (s >= WTOT) return;
  float v = 0.f;
  if (s < OFF_C2) {
    int t = s, co = t / 3072, kk = t % 3072;
    v = P.c1[(co * 768 + (kk >> 2)) * 4 + (kk & 3)];
  } else if (s < OFF_C3) {
    int t = s - OFF_C2, co = t >> 7, kk = t & 127;
    v = P.c2[(co * 32 + (kk >> 2)) * 4 + (kk & 3)];
  } else if (s < OFF_ER0A) {
    int t = s - OFF_C3, co = t >> 8, kk = t & 255, tap = kk & 3;
    if (tap < 3) v = P.c3[(co * 64 + (kk >> 2)) * 3 + tap];
  } else if (s < OFF_ER0B) {
    int t = s - OFF_ER0A, co = t >> 8, kk = t & 255, tap = kk & 3;
    if (tap < 3) v = P.er0a[(co * 64 + (kk >> 2)) * 3 + tap];
  } else if (s < OFF_ER1A) {
    int t = s - OFF_ER0B; v = P.er0b[t];
  } else if (s < OFF_ER1B) {
    int t = s - OFF_ER1A, co = t >> 8, kk = t & 255, tap = kk & 3;
    if (tap < 3) v = P.er1a[(co * 64 + (kk >> 2)) * 3 + tap];
  } else if (s < OFF_PQ) {
    int t = s - OFF_ER1B; v = P.er1b[t];
  } else if (s < OFF_DW1) {
    int t = s - OFF_PQ; v = P.pq[t];
  } else if (s < OFF_DR0A) {
    int t = s - OFF_DW1, co = t >> 8, kk = t & 255, tap = kk & 3;
    if (tap < 3) v = P.dw1[(co * 64 + (kk >> 2)) * 3 + tap];
  } else if (s < OFF_DR0B) {
    int t = s - OFF_DR0A, co = t >> 8, kk = t & 255, tap = kk & 3;
    if (tap < 3) v = P.dr0a[(co * 64 + (kk >> 2)) * 3 + tap];
  } else if (s < OFF_DR1A) {
    int t = s - OFF_DR0B; v = P.dr0b[t];
  } else if (s < OFF_DR1B) {
    int t = s - OFF_DR1A, co = t >> 8, kk = t & 255, tap = kk & 3;
    if (tap < 3) v = P.dr1a[(co * 64 + (kk >> 2)) * 3 + tap];
  } else if (s < OFF_T1) {
    int t = s - OFF_DR1B; v = P.dr1b[t];
  } else if (s < OFF_T2) {
    int t = s - OFF_T1, nn = t >> 8, kk = t & 255;
    int par = nn >> 5, co = nn & 31, ci = kk >> 2;
    int kt = tpose_kt(par, kk & 3);
    if (kt >= 0) v = P.t1[(ci * 32 + co) * 4 + kt];
  } else {
    int t = s - OFF_T2, nn = t >> 7, kk = t & 127;
    int par = nn >> 6, co = nn & 63, ci = kk >> 2;
    int kt = tpose_kt(par, kk & 3);
    if (kt >= 0) v = P.t2[(ci * 64 + co) * 4 + kt];
  }
  _Float16 h, l; splitf(v, h, l);
  WH[s] = h; WL[s] = l;
}

// --------------------------- conv1 (768->32, k4 s2) -------------------------
// Barrier-free, LDS-free. Block = 4 waves, M-tile 64 (wave w owns rows
// m0 + w*16 + lm). Each lane builds A[m][kk=quad*8..+7] = two windows
// x[ci][2m-1..2m+2], ci = c*32 + ks*8 + quad*2 + {0,1}, directly from global.
// Both 16-col output tiles computed per wave (B cols j*16+lm, j=0,1).
__global__ __launch_bounds__(256, 2) void conv1_k(
    const float* __restrict__ x, const _Float16* __restrict__ WH,
    const _Float16* __restrict__ WL, const float* __restrict__ bias,
    float* __restrict__ out) {
  const int tid = threadIdx.x;
  const int w = tid >> 6, lane = tid & 63, lm = lane & 15, quad = lane >> 4;
  const int m0 = blockIdx.x * 64, n = blockIdx.y;
  const int mrow = m0 + w * 16 + lm;          // A-operand row (output pos)
  const int pbase = 2 * mrow - 1;             // window start (odd => pbase+1 8B-aligned)
  const bool lo = pbase >= 0;                 // only false at mrow==0
  const bool hi = pbase + 3 <= 4095;          // only false at mrow==2047
  const int pc0 = lo ? pbase : 1;             // clamped (in-range dummy)
  const int pc3 = hi ? pbase + 3 : pbase + 1;
  const float* xn = x + (size_t)n * 768 * 4096;
  const float* xq = xn + (size_t)(quad * 2) * 4096;   // first row for this quad
  const _Float16* bh0 = WH + (size_t)lm * 3072 + quad * 8;
  const _Float16* bl0 = WL + (size_t)lm * 3072 + quad * 8;
  const _Float16* bh1 = bh0 + 16 * 3072;
  const _Float16* bl1 = bl0 + 16 * 3072;
  f32x4 acc1[2], acc2[2];
#pragma unroll
  for (int j = 0; j < 2; ++j)
#pragma unroll
    for (int r = 0; r < 4; ++r) { acc1[j][r] = 0.f; acc2[j][r] = 0.f; }

#pragma unroll 1
  for (int c = 0; c < 24; ++c) {
    const float* rpc = xq + (size_t)c * 32 * 4096;
    const int kb = c * 128;
#pragma unroll
    for (int ks = 0; ks < 4; ++ks) {
      const float* r0 = rpc + (size_t)ks * 8 * 4096;
      const float* r1 = r0 + 4096;
      // A windows (2 channels x 4 taps); middle float2 always in-range.
      float  t0  = r0[pc0];
      float2 v0m = *(const float2*)(r0 + pbase + 1);
      float  t3  = r0[pc3];
      float  u0  = r1[pc0];
      float2 v1m = *(const float2*)(r1 + pbase + 1);
      float  u3  = r1[pc3];
      // B fragments for both col-tiles.
      H8u b0h, b0l, b1h, b1l;
      b0h.i = *(const int4*)(bh0 + kb + ks * 32);
      b0l.i = *(const int4*)(bl0 + kb + ks * 32);
      b1h.i = *(const int4*)(bh1 + kb + ks * 32);
      b1l.i = *(const int4*)(bl1 + kb + ks * 32);
      float a[8];
      a[0] = lo ? t0 : 0.f; a[1] = v0m.x; a[2] = v0m.y; a[3] = hi ? t3 : 0.f;
      a[4] = lo ? u0 : 0.f; a[5] = v1m.x; a[6] = v1m.y; a[7] = hi ? u3 : 0.f;
      H8u ah, al;
#pragma unroll
      for (int e = 0; e < 8; ++e) {
        _Float16 h, l; splitf(a[e], h, l);
        ah.h[e] = h; al.h[e] = l;
      }
      acc1[0] = __builtin_amdgcn_mfma_f32_16x16x32_f16(ah.h, b0h.h, acc1[0], 0, 0, 0);
      acc2[0] = __builtin_amdgcn_mfma_f32_16x16x32_f16(ah.h, b0l.h, acc2[0], 0, 0, 0);
      acc2[0] = __builtin_amdgcn_mfma_f32_16x16x32_f16(al.h, b0h.h, acc2[0], 0, 0, 0);
      acc1[1] = __builtin_amdgcn_mfma_f32_16x16x32_f16(ah.h, b1h.h, acc1[1], 0, 0, 0);
      acc2[1] = __builtin_amdgcn_mfma_f32_16x16x32_f16(ah.h, b1l.h, acc2[1], 0, 0, 0);
      acc2[1] = __builtin_amdgcn_mfma_f32_16x16x32_f16(al.h, b1h.h, acc2[1], 0, 0, 0);
    }
  }
  // epilogue: relu(acc + bias); D row = quad*4 + r within the wave's 16-strip
#pragma unroll
  for (int j = 0; j < 2; ++j) {
    int col = j * 16 + lm;
    float bv = bias[col];
    float4 o;
    o.x = fmaxf(acc1[j][0] + acc2[j][0] * INV2048 + bv, 0.f);
    o.y = fmaxf(acc1[j][1] + acc2[j][1] * INV2048 + bv, 0.f);
    o.z = fmaxf(acc1[j][2] + acc2[j][2] * INV2048 + bv, 0.f);
    o.w = fmaxf(acc1[j][3] + acc2[j][3] * INV2048 + bv, 0.f);
    *(float4*)(out + ((size_t)n * 32 + col) * 2048 + m0 + w * 16 + quad * 4) = o;
  }
}

// ------------------- generic one-shot MFMA conv (M-tile 32) -----------------
template<int CI, int KP, int NT, int STRIDE,
         bool RELU_IN, bool RELU_OUT, bool BIAS, bool TPOSE, bool RESBLK>
__global__ __launch_bounds__(256) void gconv(
    const float* __restrict__ in, const _Float16* __restrict__ WH,
    const _Float16* __restrict__ WL, const float* __restrict__ bias,
    const _Float16* __restrict__ W2H, const _Float16* __restrict__ W2L,
    float* __restrict__ out, int Lin, int Lout) {
  constexpr int CP = 32 * STRIDE + 4;
  constexpr int CP4 = CP / 4;
  constexpr int AP = KP + 8;
  constexpr int KS = KP / 32;
  constexpr int NTW = (NT == 2) ? 1 : NT / 2;
  __shared__ float xs[CI * CP];
  __shared__ _Float16 Ah[32 * AP];
  __shared__ _Float16 Al[32 * AP];
  __shared__ _Float16 A2h[RESBLK ? 32 * 40 : 1];
  __shared__ _Float16 A2l[RESBLK ? 32 * 40 : 1];
  const int tid = threadIdx.x;
  const int w = tid >> 6, lane = tid & 63, lm = lane & 15, quad = lane >> 4;
  const int mt = w >> 1, ntb = (w & 1) * NTW;
  const int m0 = blockIdx.x * 32, n = blockIdx.y;
  const int base = m0 * STRIDE - 1;
  const float* inN = in + (size_t)n * CI * Lin;
  constexpr int SLOTS = CI * CP4;
#pragma unroll
  for (int it = 0; it < (SLOTS + 255) / 256; ++it) {
    int idx = it * 256 + tid;
    if (idx < SLOTS) {
      int row = idx / CP4, c4 = idx % CP4;
      int p0 = base + c4 * 4;
      const float* rp = inN + (size_t)row * Lin;
      float4 v;
      if (p0 >= 0 && p0 + 3 < Lin) v = *(const float4*)(rp + p0);
      else {
        v.x = (p0   >= 0 && p0   < Lin) ? rp[p0]   : 0.f;
        v.y = (p0+1 >= 0 && p0+1 < Lin) ? rp[p0+1] : 0.f;
        v.z = (p0+2 >= 0 && p0+2 < Lin) ? rp[p0+2] : 0.f;
        v.w = (p0+3 >= 0 && p0+3 < Lin) ? rp[p0+3] : 0.f;
      }
      *(float4*)(&xs[row * CP + c4 * 4]) = v;
    }
  }
  __syncthreads();
#pragma unroll
  for (int it = 0; it < (32 * CI) / 256; ++it) {
    int slot = it * 256 + tid;
    int ci = slot & (CI - 1), m = slot / CI;
    const float* xr = &xs[ci * CP + STRIDE * m];
    float a0 = xr[0], a1 = xr[1], a2 = xr[2], a3 = xr[3];
    if (RELU_IN) { a0 = fmaxf(a0,0.f); a1 = fmaxf(a1,0.f);
                   a2 = fmaxf(a2,0.f); a3 = fmaxf(a3,0.f); }
    P4u ph, pl;
    splitf(a0, ph.e[0], pl.e[0]); splitf(a1, ph.e[1], pl.e[1]);
    splitf(a2, ph.e[2], pl.e[2]); splitf(a3, ph.e[3], pl.e[3]);
    *(int2*)(&Ah[m * AP + ci * 4]) = ph.u;
    *(int2*)(&Al[m * AP + ci * 4]) = pl.u;
  }
  __syncthreads();
  f32x4 acc1[NTW], acc2[NTW];
#pragma unroll
  for (int j = 0; j < NTW; ++j)
#pragma unroll
    for (int r = 0; r < 4; ++r) { acc1[j][r] = 0.f; acc2[j][r] = 0.f; }
  H8u bh[2][NTW], bl[2][NTW];
#pragma unroll
  for (int j = 0; j < NTW; ++j) {
    int col = (ntb + j) * 16 + lm;
    bh[0][j].i = *(const int4*)(WH + (size_t)col * KP + quad * 8);
    bl[0][j].i = *(const int4*)(WL + (size_t)col * KP + quad * 8);
  }
#pragma unroll
  for (int ks = 0; ks < KS; ++ks) {
    int cur = ks & 1;                      // static after full unroll
    if (ks + 1 < KS) {
#pragma unroll
      for (int j = 0; j < NTW; ++j) {
        int col = (ntb + j) * 16 + lm;
        bh[cur ^ 1][j].i = *(const int4*)(WH + (size_t)col * KP + (ks+1) * 32 + quad * 8);
        bl[cur ^ 1][j].i = *(const int4*)(WL + (size_t)col * KP + (ks+1) * 32 + quad * 8);
      }
    }
    H8u ah, al;
    ah.i = *(const int4*)(&Ah[(mt * 16 + lm) * AP + ks * 32 + quad * 8]);
    al.i = *(const int4*)(&Al[(mt * 16 + lm) * AP + ks * 32 + quad * 8]);
#pragma unroll
    for (int j = 0; j < NTW; ++j) {
      acc1[j] = __builtin_amdgcn_mfma_f32_16x16x32_f16(ah.h, bh[cur][j].h, acc1[j], 0,0,0);
      acc2[j] = __builtin_amdgcn_mfma_f32_16x16x32_f16(ah.h, bl[cur][j].h, acc2[j], 0,0,0);
      acc2[j] = __builtin_amdgcn_mfma_f32_16x16x32_f16(al.h, bh[cur][j].h, acc2[j], 0,0,0);
    }
  }
  if (RESBLK) {
    int co2 = (w & 1) * 16 + lm;
#pragma unroll
    for (int r = 0; r < 4; ++r) {
      float hv = fmaxf(acc1[0][r] + acc2[0][r] * INV2048, 0.f);
      _Float16 hh, hl; splitf(hv, hh, hl);
      int m = mt * 16 + quad * 4 + r;
      A2h[m * 40 + co2] = hh; A2l[m * 40 + co2] = hl;
    }
    __syncthreads();
    f32x4 c1[2], c2[2];
#pragma unroll
    for (int j = 0; j < 2; ++j)
#pragma unroll
      for (int r = 0; r < 4; ++r) { c1[j][r] = 0.f; c2[j][r] = 0.f; }
    H8u a2h, a2l;
    a2h.i = *(const int4*)(&A2h[(mt * 16 + lm) * 40 + quad * 8]);
    a2l.i = *(const int4*)(&A2l[(mt * 16 + lm) * 40 + quad * 8]);
    int ntb2 = (w & 1) * 2;
#pragma unroll
    for (int j = 0; j < 2; ++j) {
      int col = (ntb2 + j) * 16 + lm;
      H8u wbh, wbl;
      wbh.i = *(const int4*)(W2H + col * 32 + quad * 8);
      wbl.i = *(const int4*)(W2L + col * 32 + quad * 8);
      c1[j] = __builtin_amdgcn_mfma_f32_16x16x32_f16(a2h.h, wbh.h, c1[j], 0,0,0);
      c2[j] = __builtin_amdgcn_mfma_f32_16x16x32_f16(a2h.h, wbl.h, c2[j], 0,0,0);
      c2[j] = __builtin_amdgcn_mfma_f32_16x16x32_f16(a2l.h, wbh.h, c2[j], 0,0,0);
    }
#pragma unroll
    for (int j = 0; j < 2; ++j) {
      int col = (ntb2 + j) * 16 + lm;
      float4 o;
#pragma unroll
      for (int r = 0; r < 4; ++r) {
        int m = mt * 16 + quad * 4 + r;
        float res = xs[col * CP + m + 1];
        ((float*)&o)[r] = res + c1[j][r] + c2[j][r] * INV2048;
      }
      *(float4*)(out + ((size_t)n * 64 + col) * Lout + m0 + mt * 16 + quad * 4) = o;
    }
  } else {
    constexpr int CO = TPOSE ? NT * 8 : NT * 16;
#pragma unroll
    for (int j = 0; j < NTW; ++j) {
      int col = (ntb + j) * 16 + lm;
      int par = TPOSE ? (col / CO) : 0;
      int co  = TPOSE ? (col % CO) : col;
      float bv = BIAS ? bias[co] : 0.f;
      float vr[4];
#pragma unroll
      for (int r = 0; r < 4; ++r) {
        float v = acc1[j][r] + acc2[j][r] * INV2048 + bv;
        vr[r] = RELU_OUT ? fmaxf(v, 0.f) : v;
      }
      if (TPOSE) {
#pragma unroll
        for (int r = 0; r < 4; ++r) {
          int m = m0 + mt * 16 + quad * 4 + r;
          out[((size_t)n * CO + co) * Lout + 2 * m + par] = vr[r];
        }
      } else {
        float4 o; o.x = vr[0]; o.y = vr[1]; o.z = vr[2]; o.w = vr[3];
        *(float4*)(out + ((size_t)n * CO + co) * Lout + m0 + mt * 16 + quad * 4) = o;
      }
    }
  }
}

// ------------------------------ codebook norms ------------------------------
__global__ void enorm_k(const float* __restrict__ emb, float* __restrict__ en) {
  int e = blockIdx.x * blockDim.x + threadIdx.x;
  if (e >= 512) return;
  float s = 0.f;
  const float* r = emb + (size_t)e * 64;
  for (int c = 0; c < 64; ++c) s = fmaf(r[c], r[c], s);
  en[e] = s;
}

// ------------------ fused prevq (1x1, relu-in) + VQ -------------------------
__global__ __launch_bounds__(256) void vq_fused(
    const float* __restrict__ sIn, const _Float16* __restrict__ PQH,
    const _Float16* __restrict__ PQL, const float* __restrict__ pqb,
    const float* __restrict__ emb, const float* __restrict__ en,
    float* __restrict__ q) {
  __shared__ float xs[64 * 68];
  __shared__ _Float16 Ah[64 * 72];
  __shared__ _Float16 Al[64 * 72];
  __shared__ float zl[64 * 65];
  __shared__ float dred[4 * 64];
  __shared__ int   ired[4 * 64];
  __shared__ int   idxs[64];
  const int tid = threadIdx.x;
  const int w = tid >> 6, lane = tid & 63, lm = lane & 15, quad = lane >> 4;
  const int n = blockIdx.y, t0 = blockIdx.x * 64;
#pragma unroll
  for (int it = 0; it < 4; ++it) {
    int idx = it * 256 + tid;
    int row = idx >> 4, c4 = idx & 15;
    float4 v = *(const float4*)(sIn + ((size_t)n * 64 + row) * 1024 + t0 + c4 * 4);
    *(float4*)(&xs[row * 68 + c4 * 4]) = v;
  }
  __syncthreads();
#pragma unroll
  for (int it = 0; it < 16; ++it) {
    int slot = it * 256 + tid;
    int ci = slot & 63, t = slot >> 6;
    float v = fmaxf(xs[ci * 68 + t], 0.f);
    _Float16 h, l; splitf(v, h, l);
    Ah[t * 72 + ci] = h; Al[t * 72 + ci] = l;
  }
  __syncthreads();
  f32x4 a1[4], a2[4];
#pragma unroll
  for (int j = 0; j < 4; ++j)
#pragma unroll
    for (int r = 0; r < 4; ++r) { a1[j][r] = 0.f; a2[j][r] = 0.f; }
#pragma unroll
  for (int ks = 0; ks < 2; ++ks) {
    H8u ah, al;
    ah.i = *(const int4*)(&Ah[(w * 16 + lm) * 72 + ks * 32 + quad * 8]);
    al.i = *(const int4*)(&Al[(w * 16 + lm) * 72 + ks * 32 + quad * 8]);
#pragma unroll
    for (int j = 0; j < 4; ++j) {
      int col = j * 16 + lm;
      H8u bh, bl;
      bh.i = *(const int4*)(PQH + col * 64 + ks * 32 + quad * 8);
      bl.i = *(const int4*)(PQL + col * 64 + ks * 32 + quad * 8);
      a1[j] = __builtin_amdgcn_mfma_f32_16x16x32_f16(ah.h, bh.h, a1[j], 0,0,0);
      a2[j] = __builtin_amdgcn_mfma_f32_16x16x32_f16(ah.h, bl.h, a2[j], 0,0,0);
      a2[j] = __builtin_amdgcn_mfma_f32_16x16x32_f16(al.h, bh.h, a2[j], 0,0,0);
    }
  }
#pragma unroll
  for (int j = 0; j < 4; ++j) {
    int col = j * 16 + lm;
    float bv = pqb[col];
#pragma unroll
    for (int r = 0; r < 4; ++r) {
      int t = w * 16 + quad * 4 + r;
      zl[t * 65 + col] = a1[j][r] + a2[j][r] * INV2048 + bv;
    }
  }
  __syncthreads();
  int tt = tid & 63, cq = tid >> 6;
  float zv[64];
#pragma unroll
  for (int c = 0; c < 64; ++c) zv[c] = zl[tt * 65 + c];
  float best = 1e30f; int bidx = 0;
  for (int e = cq * 128; e < cq * 128 + 128; ++e) {
    const float* er = emb + (size_t)e * 64;
    float dot = 0.f;
#pragma unroll
    for (int c = 0; c < 64; ++c) dot = fmaf(zv[c], er[c], dot);
    float d = en[e] - 2.f * dot;
    if (d < best) { best = d; bidx = e; }
  }
  dred[cq * 64 + tt] = best;
  ired[cq * 64 + tt] = bidx;
  __syncthreads();
  if (cq == 0) {
    for (int j = 1; j < 4; ++j) {
      float d = dred[j * 64 + tt]; int i2 = ired[j * 64 + tt];
      if (d < best || (d == best && i2 < bidx)) { best = d; bidx = i2; }
    }
    idxs[tt] = bidx;
  }
  __syncthreads();
  for (int it = 0; it < 16; ++it) {
    int c = cq * 16 + it;
    q[((size_t)n * 64 + c) * 1024 + t0 + tt] = emb[(size_t)idxs[tt] * 64 + c];
  }
}

// ---------------------------------------------------------------------------
extern "C" void kernel_launch(void* const* d_in, const int* in_sizes, int n_in,
                              void* d_out, int out_size, void* d_ws, size_t ws_size,
                              hipStream_t stream) {
  const float* x        = (const float*)d_in[0];
  const float* enc_b1   = (const float*)d_in[2];
  const float* enc_b2   = (const float*)d_in[4];
  const float* enc_b3   = (const float*)d_in[6];
  const float* prevq_b  = (const float*)d_in[12];
  const float* emb      = (const float*)d_in[13];
  const float* dec_b1   = (const float*)d_in[15];
  const float* dect1_b  = (const float*)d_in[21];
  const float* dect2_b  = (const float*)d_in[23];
  float* out = (float*)d_out;

  WPtrs P;
  P.c1  = (const float*)d_in[1];  P.c2  = (const float*)d_in[3];
  P.c3  = (const float*)d_in[5];  P.er0a = (const float*)d_in[7];
  P.er0b = (const float*)d_in[8]; P.er1a = (const float*)d_in[9];
  P.er1b = (const float*)d_in[10]; P.pq = (const float*)d_in[11];
  P.dw1 = (const float*)d_in[14]; P.dr0a = (const float*)d_in[16];
  P.dr0b = (const float*)d_in[17]; P.dr1a = (const float*)d_in[18];
  P.dr1b = (const float*)d_in[19]; P.t1 = (const float*)d_in[20];
  P.t2  = (const float*)d_in[22];

  float* A  = (float*)d_ws;                   // 1M floats
  float* B  = A + (1u << 20);                 // 1M floats
  float* EN = B + (1u << 20);                 // 512 floats
  _Float16* WH = (_Float16*)(EN + 1024);      // WTOT f16
  _Float16* WL = WH + WTOT;

  dim3 blk(256);
  prep_k<<<dim3((WTOT + 255) / 256), blk, 0, stream>>>(P, WH, WL);
  enorm_k<<<dim3(2), blk, 0, stream>>>(emb, EN);
  // encoder
  conv1_k<<<dim3(32, 16), blk, 0, stream>>>(x, WH + OFF_C1, WL + OFF_C1, enc_b1, A);
  gconv<32,128,4,2, false,true,true, false,false><<<dim3(32,16), blk, 0, stream>>>(
      A, WH+OFF_C2, WL+OFF_C2, enc_b2, nullptr, nullptr, B, 2048, 1024);
  gconv<64,256,4,1, false,false,true, false,false><<<dim3(32,16), blk, 0, stream>>>(
      B, WH+OFF_C3, WL+OFF_C3, enc_b3, nullptr, nullptr, A, 1024, 1024);
  gconv<64,256,2,1, true,false,false, false,true><<<dim3(32,16), blk, 0, stream>>>(
      A, WH+OFF_ER0A, WL+OFF_ER0A, nullptr, WH+OFF_ER0B, WL+OFF_ER0B, B, 1024, 1024);
  gconv<64,256,2,1, true,false,false, false,true><<<dim3(32,16), blk, 0, stream>>>(
      B, WH+OFF_ER1A, WL+OFF_ER1A, nullptr, WH+OFF_ER1B, WL+OFF_ER1B, A, 1024, 1024);
  // VQ (prevq + relu fused)
  vq_fused<<<dim3(16,16), blk, 0, stream>>>(A, WH+OFF_PQ, WL+OFF_PQ, prevq_b, emb, EN, B);
  // decoder
  gconv<64,256,4,1, false,false,true, false,false><<<dim3(32,16), blk, 0, stream>>>(
      B, WH+OFF_DW1, WL+OFF_DW1, dec_b1, nullptr, nullptr, A, 1024, 1024);
  gconv<64,256,2,1, true,false,false, false,true><<<dim3(32,16), blk, 0, stream>>>(
      A, WH+OFF_DR0A, WL+OFF_DR0A, nullptr, WH+OFF_DR0B, WL+OFF_DR0B, B, 1024, 1024);
  gconv<64,256,2,1, true,false,false, false,true><<<dim3(32,16), blk, 0, stream>>>(
      B, WH+OFF_DR1A, WL+OFF_DR1A, nullptr, WH+OFF_DR1B, WL+OFF_DR1B, A, 1024, 1024);
  gconv<64,256,4,1, true,true,true, true,false><<<dim3(32,16), blk, 0, stream>>>(
      A, WH+OFF_T1, WL+OFF_T1, dect1_b, nullptr, nullptr, B, 1024, 2048);
  gconv<32,128,8,1, false,false,true, true,false><<<dim3(64,16), blk, 0, stream>>>(
      B, WH+OFF_T2, WL+OFF_T2, dect2_b, nullptr, nullptr, out, 2048, 4096);
}

// Round 3
// 633.246 us; speedup vs baseline: 1.0775x; 1.0156x over previous
//
#include <hip/hip_runtime.h>

// ---------------------------------------------------------------------------
// VQ-VAE forward — split-fp16 MFMA everywhere.
// x = h + l*2^-11 (l prescaled by 2^11), w likewise; acc1 = h*wh,
// acc2 = h*wl + l*wh; result = acc1 + acc2/2048.  (fp32-accurate)
// Verified MFMA mapping: A[m=lane&15][k=quad*8+j] (8 consecutive k),
// B rows [n][kk] (8 consecutive kk at col n=lane&15), D col=lane&15,
// row=quad*4+reg.  kk = ci*4 + tap, tap padded to 4 with zero weights.
// R3 lesson: NEVER index register arrays with runtime values.
// R4/R5: conv1 barrier-free + LDS-free (227->178us). Post-mortem: still
// latency-bound — occupancy was GRID-limited (512 blocks x 4 waves = 2048
// waves = 25% of 8192 slots; VGPR=40 allows 8 waves/SIMD but grid can't
// fill them), and ~24 HBM loads/c-iter drain at ~900cyc with only 2
// waves/SIMD to hide them (17.8k cyc per c-iter measured).
// R6 change: SPLIT-K conv1. blockIdx.z splits the 24 c-chunks into up to 4
// parts -> 2048 blocks = 32 waves/CU potential. Raw partials (no bias/relu)
// land in workspace planes; conv2's staging loop sums the planes and applies
// bias+relu on load (partials are only 4MB/plane; no atomics needed).
// nparts chosen from ws_size at launch (4 -> 2 -> 1 fallback).
// ---------------------------------------------------------------------------

typedef _Float16 half8 __attribute__((ext_vector_type(8)));
typedef float f32x4 __attribute__((ext_vector_type(4)));
union H8u { half8 h; int4 i; };
union P4u { _Float16 e[4]; int2 u; };

__device__ __forceinline__ void splitf(float v, _Float16& h, _Float16& l) {
  h = (_Float16)v; l = (_Float16)((v - (float)h) * 2048.0f);
}
#define INV2048 (1.0f / 2048.0f)

// ---- prepped-weight layout offsets (f16 elements) ----
#define OFF_C1   0        // conv1  [32][3072]
#define OFF_C2   98304    // conv2  [64][128]
#define OFF_C3   106496   // conv3  [64][256]
#define OFF_ER0A 122880   // enc r0 conv3 [32][256]
#define OFF_ER0B 131072   // enc r0 1x1   [64][32]
#define OFF_ER1A 133120
#define OFF_ER1B 141312
#define OFF_PQ   143360   // prevq [64][64]
#define OFF_DW1  147456   // dec conv1 [64][256]
#define OFF_DR0A 163840
#define OFF_DR0B 172032
#define OFF_DR1A 174080
#define OFF_DR1B 182272
#define OFF_T1   184320   // convT1 [64=par*32+co][256]
#define OFF_T2   200704   // convT2 [128=par*64+co][128]
#define WTOT     217088

struct WPtrs {
  const float *c1, *c2, *c3, *er0a, *er0b, *er1a, *er1b, *pq,
              *dw1, *dr0a, *dr0b, *dr1a, *dr1b, *t1, *t2;
};

__device__ __forceinline__ int tpose_kt(int par, int tap) {
  if (par == 0) { if (tap == 0) return 3; if (tap == 1) return 1; }
  else          { if (tap == 1) return 2; if (tap == 2) return 0; }
  return -1;
}

__global__ __launch_bounds__(256) void prep_k(WPtrs P, _Float16* __restrict__ WH,
                                              _Float16* __restrict__ WL) {
  int s = blockIdx.x * 256 + threadIdx.x;
  if (s >= WTOT) return;
  float v = 0.f;
  if (s < OFF_C2) {
    int t = s, co = t / 3072, kk = t % 3072;
    v = P.c1[(co * 768 + (kk >> 2)) * 4 + (kk & 3)];
  } else if (s < OFF_C3) {
    int t = s - OFF_C2, co = t >> 7, kk = t & 127;
    v = P.c2[(co * 32 + (kk >> 2)) * 4 + (kk & 3)];
  } else if (s < OFF_ER0A) {
    int t = s - OFF_C3, co = t >> 8, kk = t & 255, tap = kk & 3;
    if (tap < 3) v = P.c3[(co * 64 + (kk >> 2)) * 3 + tap];
  } else if (s < OFF_ER0B) {
    int t = s - OFF_ER0A, co = t >> 8, kk = t & 255, tap = kk & 3;
    if (tap < 3) v = P.er0a[(co * 64 + (kk >> 2)) * 3 + tap];
  } else if (s < OFF_ER1A) {
    int t = s - OFF_ER0B; v = P.er0b[t];
  } else if (s < OFF_ER1B) {
    int t = s - OFF_ER1A, co = t >> 8, kk = t & 255, tap = kk & 3;
    if (tap < 3) v = P.er1a[(co * 64 + (kk >> 2)) * 3 + tap];
  } else if (s < OFF_PQ) {
    int t = s - OFF_ER1B; v = P.er1b[t];
  } else if (s < OFF_DW1) {
    int t = s - OFF_PQ; v = P.pq[t];
  } else if (s < OFF_DR0A) {
    int t = s - OFF_DW1, co = t >> 8, kk = t & 255, tap = kk & 3;
    if (tap < 3) v = P.dw1[(co * 64 + (kk >> 2)) * 3 + tap];
  } else if (s < OFF_DR0B) {
    int t = s - OFF_DR0A, co = t >> 8, kk = t & 255, tap = kk & 3;
    if (tap < 3) v = P.dr0a[(co * 64 + (kk >> 2)) * 3 + tap];
  } else if (s < OFF_DR1A) {
    int t = s - OFF_DR0B; v = P.dr0b[t];
  } else if (s < OFF_DR1B) {
    int t = s - OFF_DR1A, co = t >> 8, kk = t & 255, tap = kk & 3;
    if (tap < 3) v = P.dr1a[(co * 64 + (kk >> 2)) * 3 + tap];
  } else if (s < OFF_T1) {
    int t = s - OFF_DR1B; v = P.dr1b[t];
  } else if (s < OFF_T2) {
    int t = s - OFF_T1, nn = t >> 8, kk = t & 255;
    int par = nn >> 5, co = nn & 31, ci = kk >> 2;
    int kt = tpose_kt(par, kk & 3);
    if (kt >= 0) v = P.t1[(ci * 32 + co) * 4 + kt];
  } else {
    int t = s - OFF_T2, nn = t >> 7, kk = t & 127;
    int par = nn >> 6, co = nn & 63, ci = kk >> 2;
    int kt = tpose_kt(par, kk & 3);
    if (kt >= 0) v = P.t2[(ci * 64 + co) * 4 + kt];
  }
  _Float16 h, l; splitf(v, h, l);
  WH[s] = h; WL[s] = l;
}

// --------------------------- conv1 (768->32, k4 s2) -------------------------
// Barrier-free, LDS-free, SPLIT-K. Block = 4 waves, M-tile 64 (wave w owns
// rows m0 + w*16 + lm). blockIdx.z = kpart; each part covers `cchunks`
// 32-channel chunks and writes a raw fp32 partial plane (no bias/relu) at
// Pout + kpart*16*32*2048. conv2 sums the planes on load.
__global__ __launch_bounds__(256, 2) void conv1_k(
    const float* __restrict__ x, const _Float16* __restrict__ WH,
    const _Float16* __restrict__ WL, float* __restrict__ Pout, int cchunks) {
  const int tid = threadIdx.x;
  const int w = tid >> 6, lane = tid & 63, lm = lane & 15, quad = lane >> 4;
  const int m0 = blockIdx.x * 64, n = blockIdx.y, kpart = blockIdx.z;
  const int mrow = m0 + w * 16 + lm;          // A-operand row (output pos)
  const int pbase = 2 * mrow - 1;             // window start (odd => pbase+1 8B-aligned)
  const bool lo = pbase >= 0;                 // only false at mrow==0
  const bool hi = pbase + 3 <= 4095;          // only false at mrow==2047
  const int pc0 = lo ? pbase : 1;             // clamped (in-range dummy)
  const int pc3 = hi ? pbase + 3 : pbase + 1;
  const float* xn = x + (size_t)n * 768 * 4096;
  const float* xq = xn + (size_t)(quad * 2) * 4096;   // first row for this quad
  const _Float16* bh0 = WH + (size_t)lm * 3072 + quad * 8;
  const _Float16* bl0 = WL + (size_t)lm * 3072 + quad * 8;
  const _Float16* bh1 = bh0 + 16 * 3072;
  const _Float16* bl1 = bl0 + 16 * 3072;
  f32x4 acc1[2], acc2[2];
#pragma unroll
  for (int j = 0; j < 2; ++j)
#pragma unroll
    for (int r = 0; r < 4; ++r) { acc1[j][r] = 0.f; acc2[j][r] = 0.f; }

  const int c0 = kpart * cchunks;
#pragma unroll 1
  for (int cc = 0; cc < cchunks; ++cc) {
    const int c = c0 + cc;
    const float* rpc = xq + (size_t)c * 32 * 4096;
    const int kb = c * 128;
#pragma unroll
    for (int ks = 0; ks < 4; ++ks) {
      const float* r0 = rpc + (size_t)ks * 8 * 4096;
      const float* r1 = r0 + 4096;
      // A windows (2 channels x 4 taps); middle float2 always in-range.
      float  t0  = r0[pc0];
      float2 v0m = *(const float2*)(r0 + pbase + 1);
      float  t3  = r0[pc3];
      float  u0  = r1[pc0];
      float2 v1m = *(const float2*)(r1 + pbase + 1);
      float  u3  = r1[pc3];
      // B fragments for both col-tiles.
      H8u b0h, b0l, b1h, b1l;
      b0h.i = *(const int4*)(bh0 + kb + ks * 32);
      b0l.i = *(const int4*)(bl0 + kb + ks * 32);
      b1h.i = *(const int4*)(bh1 + kb + ks * 32);
      b1l.i = *(const int4*)(bl1 + kb + ks * 32);
      float a[8];
      a[0] = lo ? t0 : 0.f; a[1] = v0m.x; a[2] = v0m.y; a[3] = hi ? t3 : 0.f;
      a[4] = lo ? u0 : 0.f; a[5] = v1m.x; a[6] = v1m.y; a[7] = hi ? u3 : 0.f;
      H8u ah, al;
#pragma unroll
      for (int e = 0; e < 8; ++e) {
        _Float16 h, l; splitf(a[e], h, l);
        ah.h[e] = h; al.h[e] = l;
      }
      acc1[0] = __builtin_amdgcn_mfma_f32_16x16x32_f16(ah.h, b0h.h, acc1[0], 0, 0, 0);
      acc2[0] = __builtin_amdgcn_mfma_f32_16x16x32_f16(ah.h, b0l.h, acc2[0], 0, 0, 0);
      acc2[0] = __builtin_amdgcn_mfma_f32_16x16x32_f16(al.h, b0h.h, acc2[0], 0, 0, 0);
      acc1[1] = __builtin_amdgcn_mfma_f32_16x16x32_f16(ah.h, b1h.h, acc1[1], 0, 0, 0);
      acc2[1] = __builtin_amdgcn_mfma_f32_16x16x32_f16(ah.h, b1l.h, acc2[1], 0, 0, 0);
      acc2[1] = __builtin_amdgcn_mfma_f32_16x16x32_f16(al.h, b1h.h, acc2[1], 0, 0, 0);
    }
  }
  // epilogue: raw partial (bias/relu deferred to conv2's staging)
#pragma unroll
  for (int j = 0; j < 2; ++j) {
    int col = j * 16 + lm;
    float4 o;
    o.x = acc1[j][0] + acc2[j][0] * INV2048;
    o.y = acc1[j][1] + acc2[j][1] * INV2048;
    o.z = acc1[j][2] + acc2[j][2] * INV2048;
    o.w = acc1[j][3] + acc2[j][3] * INV2048;
    *(float4*)(Pout + (size_t)kpart * (16 * 32 * 2048)
               + ((size_t)n * 32 + col) * 2048 + m0 + w * 16 + quad * 4) = o;
  }
}

// ------------------- generic one-shot MFMA conv (M-tile 32) -----------------
// PSUM: input is `nparts` raw partial planes (stride pplane floats); staging
// sums them, adds inbias[row], applies relu — in-range elements only.
template<int CI, int KP, int NT, int STRIDE,
         bool RELU_IN, bool RELU_OUT, bool BIAS, bool TPOSE, bool RESBLK,
         bool PSUM = false>
__global__ __launch_bounds__(256) void gconv(
    const float* __restrict__ in, const _Float16* __restrict__ WH,
    const _Float16* __restrict__ WL, const float* __restrict__ bias,
    const _Float16* __restrict__ W2H, const _Float16* __restrict__ W2L,
    float* __restrict__ out, int Lin, int Lout,
    const float* __restrict__ inbias, int nparts, int pplane) {
  constexpr int CP = 32 * STRIDE + 4;
  constexpr int CP4 = CP / 4;
  constexpr int AP = KP + 8;
  constexpr int KS = KP / 32;
  constexpr int NTW = (NT == 2) ? 1 : NT / 2;
  __shared__ float xs[CI * CP];
  __shared__ _Float16 Ah[32 * AP];
  __shared__ _Float16 Al[32 * AP];
  __shared__ _Float16 A2h[RESBLK ? 32 * 40 : 1];
  __shared__ _Float16 A2l[RESBLK ? 32 * 40 : 1];
  const int tid = threadIdx.x;
  const int w = tid >> 6, lane = tid & 63, lm = lane & 15, quad = lane >> 4;
  const int mt = w >> 1, ntb = (w & 1) * NTW;
  const int m0 = blockIdx.x * 32, n = blockIdx.y;
  const int base = m0 * STRIDE - 1;
  const float* inN = in + (size_t)n * CI * Lin;
  constexpr int SLOTS = CI * CP4;
#pragma unroll
  for (int it = 0; it < (SLOTS + 255) / 256; ++it) {
    int idx = it * 256 + tid;
    if (idx < SLOTS) {
      int row = idx / CP4, c4 = idx % CP4;
      int p0 = base + c4 * 4;
      const float* rp = inN + (size_t)row * Lin;
      float4 v;
      if (PSUM) {
        v.x = 0.f; v.y = 0.f; v.z = 0.f; v.w = 0.f;
        bool i0 = (p0   >= 0 && p0   < Lin);
        bool i1 = (p0+1 >= 0 && p0+1 < Lin);
        bool i2 = (p0+2 >= 0 && p0+2 < Lin);
        bool i3 = (p0+3 >= 0 && p0+3 < Lin);
        bool full = (p0 >= 0 && p0 + 3 < Lin);
        for (int p = 0; p < nparts; ++p) {
          const float* rpp = rp + (size_t)p * pplane;
          if (full) {
            float4 t = *(const float4*)(rpp + p0);
            v.x += t.x; v.y += t.y; v.z += t.z; v.w += t.w;
          } else {
            if (i0) v.x += rpp[p0];
            if (i1) v.y += rpp[p0+1];
            if (i2) v.z += rpp[p0+2];
            if (i3) v.w += rpp[p0+3];
          }
        }
        float bv = inbias[row];
        v.x = i0 ? fmaxf(v.x + bv, 0.f) : 0.f;
        v.y = i1 ? fmaxf(v.y + bv, 0.f) : 0.f;
        v.z = i2 ? fmaxf(v.z + bv, 0.f) : 0.f;
        v.w = i3 ? fmaxf(v.w + bv, 0.f) : 0.f;
      } else {
        if (p0 >= 0 && p0 + 3 < Lin) v = *(const float4*)(rp + p0);
        else {
          v.x = (p0   >= 0 && p0   < Lin) ? rp[p0]   : 0.f;
          v.y = (p0+1 >= 0 && p0+1 < Lin) ? rp[p0+1] : 0.f;
          v.z = (p0+2 >= 0 && p0+2 < Lin) ? rp[p0+2] : 0.f;
          v.w = (p0+3 >= 0 && p0+3 < Lin) ? rp[p0+3] : 0.f;
        }
      }
      *(float4*)(&xs[row * CP + c4 * 4]) = v;
    }
  }
  __syncthreads();
#pragma unroll
  for (int it = 0; it < (32 * CI) / 256; ++it) {
    int slot = it * 256 + tid;
    int ci = slot & (CI - 1), m = slot / CI;
    const float* xr = &xs[ci * CP + STRIDE * m];
    float a0 = xr[0], a1 = xr[1], a2 = xr[2], a3 = xr[3];
    if (RELU_IN) { a0 = fmaxf(a0,0.f); a1 = fmaxf(a1,0.f);
                   a2 = fmaxf(a2,0.f); a3 = fmaxf(a3,0.f); }
    P4u ph, pl;
    splitf(a0, ph.e[0], pl.e[0]); splitf(a1, ph.e[1], pl.e[1]);
    splitf(a2, ph.e[2], pl.e[2]); splitf(a3, ph.e[3], pl.e[3]);
    *(int2*)(&Ah[m * AP + ci * 4]) = ph.u;
    *(int2*)(&Al[m * AP + ci * 4]) = pl.u;
  }
  __syncthreads();
  f32x4 acc1[NTW], acc2[NTW];
#pragma unroll
  for (int j = 0; j < NTW; ++j)
#pragma unroll
    for (int r = 0; r < 4; ++r) { acc1[j][r] = 0.f; acc2[j][r] = 0.f; }
  H8u bh[2][NTW], bl[2][NTW];
#pragma unroll
  for (int j = 0; j < NTW; ++j) {
    int col = (ntb + j) * 16 + lm;
    bh[0][j].i = *(const int4*)(WH + (size_t)col * KP + quad * 8);
    bl[0][j].i = *(const int4*)(WL + (size_t)col * KP + quad * 8);
  }
#pragma unroll
  for (int ks = 0; ks < KS; ++ks) {
    int cur = ks & 1;                      // static after full unroll
    if (ks + 1 < KS) {
#pragma unroll
      for (int j = 0; j < NTW; ++j) {
        int col = (ntb + j) * 16 + lm;
        bh[cur ^ 1][j].i = *(const int4*)(WH + (size_t)col * KP + (ks+1) * 32 + quad * 8);
        bl[cur ^ 1][j].i = *(const int4*)(WL + (size_t)col * KP + (ks+1) * 32 + quad * 8);
      }
    }
    H8u ah, al;
    ah.i = *(const int4*)(&Ah[(mt * 16 + lm) * AP + ks * 32 + quad * 8]);
    al.i = *(const int4*)(&Al[(mt * 16 + lm) * AP + ks * 32 + quad * 8]);
#pragma unroll
    for (int j = 0; j < NTW; ++j) {
      acc1[j] = __builtin_amdgcn_mfma_f32_16x16x32_f16(ah.h, bh[cur][j].h, acc1[j], 0,0,0);
      acc2[j] = __builtin_amdgcn_mfma_f32_16x16x32_f16(ah.h, bl[cur][j].h, acc2[j], 0,0,0);
      acc2[j] = __builtin_amdgcn_mfma_f32_16x16x32_f16(al.h, bh[cur][j].h, acc2[j], 0,0,0);
    }
  }
  if (RESBLK) {
    int co2 = (w & 1) * 16 + lm;
#pragma unroll
    for (int r = 0; r < 4; ++r) {
      float hv = fmaxf(acc1[0][r] + acc2[0][r] * INV2048, 0.f);
      _Float16 hh, hl; splitf(hv, hh, hl);
      int m = mt * 16 + quad * 4 + r;
      A2h[m * 40 + co2] = hh; A2l[m * 40 + co2] = hl;
    }
    __syncthreads();
    f32x4 c1[2], c2[2];
#pragma unroll
    for (int j = 0; j < 2; ++j)
#pragma unroll
      for (int r = 0; r < 4; ++r) { c1[j][r] = 0.f; c2[j][r] = 0.f; }
    H8u a2h, a2l;
    a2h.i = *(const int4*)(&A2h[(mt * 16 + lm) * 40 + quad * 8]);
    a2l.i = *(const int4*)(&A2l[(mt * 16 + lm) * 40 + quad * 8]);
    int ntb2 = (w & 1) * 2;
#pragma unroll
    for (int j = 0; j < 2; ++j) {
      int col = (ntb2 + j) * 16 + lm;
      H8u wbh, wbl;
      wbh.i = *(const int4*)(W2H + col * 32 + quad * 8);
      wbl.i = *(const int4*)(W2L + col * 32 + quad * 8);
      c1[j] = __builtin_amdgcn_mfma_f32_16x16x32_f16(a2h.h, wbh.h, c1[j], 0,0,0);
      c2[j] = __builtin_amdgcn_mfma_f32_16x16x32_f16(a2h.h, wbl.h, c2[j], 0,0,0);
      c2[j] = __builtin_amdgcn_mfma_f32_16x16x32_f16(a2l.h, wbh.h, c2[j], 0,0,0);
    }
#pragma unroll
    for (int j = 0; j < 2; ++j) {
      int col = (ntb2 + j) * 16 + lm;
      float4 o;
#pragma unroll
      for (int r = 0; r < 4; ++r) {
        int m = mt * 16 + quad * 4 + r;
        float res = xs[col * CP + m + 1];
        ((float*)&o)[r] = res + c1[j][r] + c2[j][r] * INV2048;
      }
      *(float4*)(out + ((size_t)n * 64 + col) * Lout + m0 + mt * 16 + quad * 4) = o;
    }
  } else {
    constexpr int CO = TPOSE ? NT * 8 : NT * 16;
#pragma unroll
    for (int j = 0; j < NTW; ++j) {
      int col = (ntb + j) * 16 + lm;
      int par = TPOSE ? (col / CO) : 0;
      int co  = TPOSE ? (col % CO) : col;
      float bv = BIAS ? bias[co] : 0.f;
      float vr[4];
#pragma unroll
      for (int r = 0; r < 4; ++r) {
        float v = acc1[j][r] + acc2[j][r] * INV2048 + bv;
        vr[r] = RELU_OUT ? fmaxf(v, 0.f) : v;
      }
      if (TPOSE) {
#pragma unroll
        for (int r = 0; r < 4; ++r) {
          int m = m0 + mt * 16 + quad * 4 + r;
          out[((size_t)n * CO + co) * Lout + 2 * m + par] = vr[r];
        }
      } else {
        float4 o; o.x = vr[0]; o.y = vr[1]; o.z = vr[2]; o.w = vr[3];
        *(float4*)(out + ((size_t)n * CO + co) * Lout + m0 + mt * 16 + quad * 4) = o;
      }
    }
  }
}

// ------------------------------ codebook norms ------------------------------
__global__ void enorm_k(const float* __restrict__ emb, float* __restrict__ en) {
  int e = blockIdx.x * blockDim.x + threadIdx.x;
  if (e >= 512) return;
  float s = 0.f;
  const float* r = emb + (size_t)e * 64;
  for (int c = 0; c < 64; ++c) s = fmaf(r[c], r[c], s);
  en[e] = s;
}

// ------------------ fused prevq (1x1, relu-in) + VQ -------------------------
__global__ __launch_bounds__(256) void vq_fused(
    const float* __restrict__ sIn, const _Float16* __restrict__ PQH,
    const _Float16* __restrict__ PQL, const float* __restrict__ pqb,
    const float* __restrict__ emb, const float* __restrict__ en,
    float* __restrict__ q) {
  __shared__ float xs[64 * 68];
  __shared__ _Float16 Ah[64 * 72];
  __shared__ _Float16 Al[64 * 72];
  __shared__ float zl[64 * 65];
  __shared__ float dred[4 * 64];
  __shared__ int   ired[4 * 64];
  __shared__ int   idxs[64];
  const int tid = threadIdx.x;
  const int w = tid >> 6, lane = tid & 63, lm = lane & 15, quad = lane >> 4;
  const int n = blockIdx.y, t0 = blockIdx.x * 64;
#pragma unroll
  for (int it = 0; it < 4; ++it) {
    int idx = it * 256 + tid;
    int row = idx >> 4, c4 = idx & 15;
    float4 v = *(const float4*)(sIn + ((size_t)n * 64 + row) * 1024 + t0 + c4 * 4);
    *(float4*)(&xs[row * 68 + c4 * 4]) = v;
  }
  __syncthreads();
#pragma unroll
  for (int it = 0; it < 16; ++it) {
    int slot = it * 256 + tid;
    int ci = slot & 63, t = slot >> 6;
    float v = fmaxf(xs[ci * 68 + t], 0.f);
    _Float16 h, l; splitf(v, h, l);
    Ah[t * 72 + ci] = h; Al[t * 72 + ci] = l;
  }
  __syncthreads();
  f32x4 a1[4], a2[4];
#pragma unroll
  for (int j = 0; j < 4; ++j)
#pragma unroll
    for (int r = 0; r < 4; ++r) { a1[j][r] = 0.f; a2[j][r] = 0.f; }
#pragma unroll
  for (int ks = 0; ks < 2; ++ks) {
    H8u ah, al;
    ah.i = *(const int4*)(&Ah[(w * 16 + lm) * 72 + ks * 32 + quad * 8]);
    al.i = *(const int4*)(&Al[(w * 16 + lm) * 72 + ks * 32 + quad * 8]);
#pragma unroll
    for (int j = 0; j < 4; ++j) {
      int col = j * 16 + lm;
      H8u bh, bl;
      bh.i = *(const int4*)(PQH + col * 64 + ks * 32 + quad * 8);
      bl.i = *(const int4*)(PQL + col * 64 + ks * 32 + quad * 8);
      a1[j] = __builtin_amdgcn_mfma_f32_16x16x32_f16(ah.h, bh.h, a1[j], 0,0,0);
      a2[j] = __builtin_amdgcn_mfma_f32_16x16x32_f16(ah.h, bl.h, a2[j], 0,0,0);
      a2[j] = __builtin_amdgcn_mfma_f32_16x16x32_f16(al.h, bh.h, a2[j], 0,0,0);
    }
  }
#pragma unroll
  for (int j = 0; j < 4; ++j) {
    int col = j * 16 + lm;
    float bv = pqb[col];
#pragma unroll
    for (int r = 0; r < 4; ++r) {
      int t = w * 16 + quad * 4 + r;
      zl[t * 65 + col] = a1[j][r] + a2[j][r] * INV2048 + bv;
    }
  }
  __syncthreads();
  int tt = tid & 63, cq = tid >> 6;
  float zv[64];
#pragma unroll
  for (int c = 0; c < 64; ++c) zv[c] = zl[tt * 65 + c];
  float best = 1e30f; int bidx = 0;
  for (int e = cq * 128; e < cq * 128 + 128; ++e) {
    const float* er = emb + (size_t)e * 64;
    float dot = 0.f;
#pragma unroll
    for (int c = 0; c < 64; ++c) dot = fmaf(zv[c], er[c], dot);
    float d = en[e] - 2.f * dot;
    if (d < best) { best = d; bidx = e; }
  }
  dred[cq * 64 + tt] = best;
  ired[cq * 64 + tt] = bidx;
  __syncthreads();
  if (cq == 0) {
    for (int j = 1; j < 4; ++j) {
      float d = dred[j * 64 + tt]; int i2 = ired[j * 64 + tt];
      if (d < best || (d == best && i2 < bidx)) { best = d; bidx = i2; }
    }
    idxs[tt] = bidx;
  }
  __syncthreads();
  for (int it = 0; it < 16; ++it) {
    int c = cq * 16 + it;
    q[((size_t)n * 64 + c) * 1024 + t0 + tt] = emb[(size_t)idxs[tt] * 64 + c];
  }
}

// ---------------------------------------------------------------------------
extern "C" void kernel_launch(void* const* d_in, const int* in_sizes, int n_in,
                              void* d_out, int out_size, void* d_ws, size_t ws_size,
                              hipStream_t stream) {
  const float* x        = (const float*)d_in[0];
  const float* enc_b1   = (const float*)d_in[2];
  const float* enc_b2   = (const float*)d_in[4];
  const float* enc_b3   = (const float*)d_in[6];
  const float* prevq_b  = (const float*)d_in[12];
  const float* emb      = (const float*)d_in[13];
  const float* dec_b1   = (const float*)d_in[15];
  const float* dect1_b  = (const float*)d_in[21];
  const float* dect2_b  = (const float*)d_in[23];
  float* out = (float*)d_out;

  WPtrs P;
  P.c1  = (const float*)d_in[1];  P.c2  = (const float*)d_in[3];
  P.c3  = (const float*)d_in[5];  P.er0a = (const float*)d_in[7];
  P.er0b = (const float*)d_in[8]; P.er1a = (const float*)d_in[9];
  P.er1b = (const float*)d_in[10]; P.pq = (const float*)d_in[11];
  P.dw1 = (const float*)d_in[14]; P.dr0a = (const float*)d_in[16];
  P.dr0b = (const float*)d_in[17]; P.dr1a = (const float*)d_in[18];
  P.dr1b = (const float*)d_in[19]; P.t1 = (const float*)d_in[20];
  P.t2  = (const float*)d_in[22];

  float* A  = (float*)d_ws;                   // 1M floats
  float* B  = A + (1u << 20);                 // 1M floats
  float* EN = B + (1u << 20);                 // 512 floats
  _Float16* WH = (_Float16*)(EN + 1024);      // WTOT f16
  _Float16* WL = WH + WTOT;
  float* PP = (float*)(WL + WTOT);            // conv1 split-K partial planes

  // conv1 split-K: plane = 16*32*2048 floats = 4 MB. Pick nparts by ws_size.
  const size_t baseBytes = (size_t)((char*)PP - (char*)d_ws);
  const size_t planeB = (size_t)16 * 32 * 2048 * 4;
  int nparts = 1;
  float* Pbuf = A;                            // nparts==1: reuse A directly
  if (ws_size >= baseBytes + 4 * planeB) { nparts = 4; Pbuf = PP; }
  else if (ws_size >= baseBytes + 2 * planeB) { nparts = 2; Pbuf = PP; }

  dim3 blk(256);
  prep_k<<<dim3((WTOT + 255) / 256), blk, 0, stream>>>(P, WH, WL);
  enorm_k<<<dim3(2), blk, 0, stream>>>(emb, EN);
  // encoder — conv1 writes raw split-K partials; conv2 sums + bias + relu
  conv1_k<<<dim3(32, 16, nparts), blk, 0, stream>>>(x, WH + OFF_C1, WL + OFF_C1,
                                                    Pbuf, 24 / nparts);
  gconv<32,128,4,2, false,true,true, false,false, true><<<dim3(32,16), blk, 0, stream>>>(
      Pbuf, WH+OFF_C2, WL+OFF_C2, enc_b2, nullptr, nullptr, B, 2048, 1024,
      enc_b1, nparts, 16 * 32 * 2048);
  gconv<64,256,4,1, false,false,true, false,false><<<dim3(32,16), blk, 0, stream>>>(
      B, WH+OFF_C3, WL+OFF_C3, enc_b3, nullptr, nullptr, A, 1024, 1024,
      nullptr, 1, 0);
  gconv<64,256,2,1, true,false,false, false,true><<<dim3(32,16), blk, 0, stream>>>(
      A, WH+OFF_ER0A, WL+OFF_ER0A, nullptr, WH+OFF_ER0B, WL+OFF_ER0B, B, 1024, 1024,
      nullptr, 1, 0);
  gconv<64,256,2,1, true,false,false, false,true><<<dim3(32,16), blk, 0, stream>>>(
      B, WH+OFF_ER1A, WL+OFF_ER1A, nullptr, WH+OFF_ER1B, WL+OFF_ER1B, A, 1024, 1024,
      nullptr, 1, 0);
  // VQ (prevq + relu fused)
  vq_fused<<<dim3(16,16), blk, 0, stream>>>(A, WH+OFF_PQ, WL+OFF_PQ, prevq_b, emb, EN, B);
  // decoder
  gconv<64,256,4,1, false,false,true, false,false><<<dim3(32,16), blk, 0, stream>>>(
      B, WH+OFF_DW1, WL+OFF_DW1, dec_b1, nullptr, nullptr, A, 1024, 1024,
      nullptr, 1, 0);
  gconv<64,256,2,1, true,false,false, false,true><<<dim3(32,16), blk, 0, stream>>>(
      A, WH+OFF_DR0A, WL+OFF_DR0A, nullptr, WH+OFF_DR0B, WL+OFF_DR0B, B, 1024, 1024,
      nullptr, 1, 0);
  gconv<64,256,2,1, true,false,false, false,true><<<dim3(32,16), blk, 0, stream>>>(
      B, WH+OFF_DR1A, WL+OFF_DR1A, nullptr, WH+OFF_DR1B, WL+OFF_DR1B, A, 1024, 1024,
      nullptr, 1, 0);
  gconv<64,256,4,1, true,true,true, true,false><<<dim3(32,16), blk, 0, stream>>>(
      A, WH+OFF_T1, WL+OFF_T1, dect1_b, nullptr, nullptr, B, 1024, 2048,
      nullptr, 1, 0);
  gconv<32,128,8,1, false,false,true, true,false><<<dim3(64,16), blk, 0, stream>>>(
      B, WH+OFF_T2, WL+OFF_T2, dect2_b, nullptr, nullptr, out, 2048, 4096,
      nullptr, 1, 0);
}